// Round 2
// baseline (295.288 us; speedup 1.0000x reference)
//
#include <hip/hip_runtime.h>
#include <hip/hip_bf16.h>
#include <stdint.h>

#define BATCH 8
#define K_DIM 4096
#define N_DIM 16384
#define KH (K_DIM / 2)          // 2048 packed ints per output row
#define BLOCK 512               // 8 waves
#define ROWS_PER_WAVE 4
#define ROWS_PER_BLOCK 32       // 8 waves * 4 rows
#define ITERS (KH / 4 / 64)     // 8 iterations of int4 per lane

__device__ __forceinline__ float bf16lo(uint32_t u) { return __uint_as_float(u << 16); }
__device__ __forceinline__ float bf16hi(uint32_t u) { return __uint_as_float(u & 0xFFFF0000u); }

// LDS: xchunks[c] (uint4) = column c's 8 batches as bf16, at swizzled chunk
// index phys = c ^ ((c>>3)&7). Lane u's 8 columns (8u..8u+7) live in chunks
// 8u + (delta ^ (u&7)) -> each sub-read's 8-lane group covers all 8 quad-bank
// groups -> conflict-free ds_read_b128.
__global__ __launch_bounds__(BLOCK, 4)
void w4a16_gemv(const float* __restrict__ x,       // [8][4096] f32 (fp16 upcast)
                const int*   __restrict__ w,       // [16384][2048] int32 (byte each)
                const float* __restrict__ scales,  // [16384] f32
                float*       __restrict__ out)     // [8][16384] f32
{
    __shared__ uint4 xchunks[K_DIM];   // 64 KiB
    uint16_t* ldsu = (uint16_t*)xchunks;

    const int tid = threadIdx.x;

    // ---- stage x -> LDS (f32 -> bf16, transposed + swizzled) ----
    {
        const float4* xv = (const float4*)x;          // 8192 float4 total
        for (int i = tid; i < (BATCH * K_DIM) / 4; i += BLOCK) {
            float4 v = xv[i];
            int b  = i >> 10;            // 1024 float4 per batch row
            int c0 = (i & 1023) << 2;
            float vv[4] = {v.x, v.y, v.z, v.w};
            #pragma unroll
            for (int k2 = 0; k2 < 4; ++k2) {
                int c = c0 + k2;
                int phys = c ^ ((c >> 3) & 7);
                __hip_bfloat16 h = __float2bfloat16(vv[k2]);   // RNE
                ldsu[(phys << 3) + b] = *(const uint16_t*)&h;
            }
        }
    }
    __syncthreads();

    const int wave = tid >> 6;
    const int lane = tid & 63;
    const int row0 = blockIdx.x * ROWS_PER_BLOCK + wave * ROWS_PER_WAVE;

    const int4* __restrict__ wv0 = (const int4*)(w + (size_t)(row0 + 0) * KH);
    const int4* __restrict__ wv1 = (const int4*)(w + (size_t)(row0 + 1) * KH);
    const int4* __restrict__ wv2 = (const int4*)(w + (size_t)(row0 + 2) * KH);
    const int4* __restrict__ wv3 = (const int4*)(w + (size_t)(row0 + 3) * KH);

    float acc[ROWS_PER_WAVE][BATCH];
    #pragma unroll
    for (int j = 0; j < ROWS_PER_WAVE; ++j)
        #pragma unroll
        for (int b = 0; b < BATCH; ++b) acc[j][b] = 0.0f;

    #pragma unroll 2
    for (int t = 0; t < ITERS; ++t) {
        const int u = (t << 6) + lane;       // int4 index within row
        int4 q0 = wv0[u];
        int4 q1 = wv1[u];
        int4 q2 = wv2[u];
        int4 q3 = wv3[u];
        const int xork  = u & 7;
        const int cbase = u << 3;            // chunk base (column 8u)

        int qw[ROWS_PER_WAVE][4];
        qw[0][0] = q0.x; qw[0][1] = q0.y; qw[0][2] = q0.z; qw[0][3] = q0.w;
        qw[1][0] = q1.x; qw[1][1] = q1.y; qw[1][2] = q1.z; qw[1][3] = q1.w;
        qw[2][0] = q2.x; qw[2][1] = q2.y; qw[2][2] = q2.z; qw[2][3] = q2.w;
        qw[3][0] = q3.x; qw[3][1] = q3.y; qw[3][2] = q3.z; qw[3][3] = q3.w;

        #pragma unroll
        for (int m = 0; m < 4; ++m) {
            // packed int p = 4u+m covers columns 8u+2m (low nibble), 8u+2m+1 (high)
            const uint4 xa = xchunks[cbase + ((2 * m)     ^ xork)];
            const uint4 xb = xchunks[cbase + ((2 * m + 1) ^ xork)];

            float xlo[BATCH], xhi[BATCH];
            xlo[0] = bf16lo(xa.x); xlo[1] = bf16hi(xa.x);
            xlo[2] = bf16lo(xa.y); xlo[3] = bf16hi(xa.y);
            xlo[4] = bf16lo(xa.z); xlo[5] = bf16hi(xa.z);
            xlo[6] = bf16lo(xa.w); xlo[7] = bf16hi(xa.w);
            xhi[0] = bf16lo(xb.x); xhi[1] = bf16hi(xb.x);
            xhi[2] = bf16lo(xb.y); xhi[3] = bf16hi(xb.y);
            xhi[4] = bf16lo(xb.z); xhi[5] = bf16hi(xb.z);
            xhi[6] = bf16lo(xb.w); xhi[7] = bf16hi(xb.w);

            #pragma unroll
            for (int j = 0; j < ROWS_PER_WAVE; ++j) {
                const unsigned bv = ((unsigned)qw[j][m]) & 0xFFu;
                const float flo = (float)((int)((bv & 0xFu) ^ 8u) - 8);
                const float fhi = (float)((int)(((bv >> 4) & 0xFu) ^ 8u) - 8);
                #pragma unroll
                for (int b = 0; b < BATCH; ++b) {
                    acc[j][b] = fmaf(flo, xlo[b], acc[j][b]);
                    acc[j][b] = fmaf(fhi, xhi[b], acc[j][b]);
                }
            }
        }
    }

    // ---- 32-value tree reduction: 31 + 1 shuffles; value j*8+b lands on lane j*8+b ----
    float vals[32];
    #pragma unroll
    for (int j = 0; j < ROWS_PER_WAVE; ++j)
        #pragma unroll
        for (int b = 0; b < BATCH; ++b) vals[j * 8 + b] = acc[j][b];

    #pragma unroll
    for (int k = 0; k < 5; ++k) {
        const int sel = (lane >> k) & 1;
        const int n = 32 >> k;
        #pragma unroll
        for (int i = 0; i < n / 2; ++i) {
            const float a = vals[2 * i];
            const float c = vals[2 * i + 1];
            const float mine  = sel ? c : a;
            const float other = sel ? a : c;
            vals[i] = mine + __shfl_xor(other, 1 << k, 64);
        }
    }
    const float total = vals[0] + __shfl_xor(vals[0], 32, 64);

    if (lane < 32) {
        const int r = row0 + (lane >> 3);      // value index == lane: j = lane>>3, b = lane&7
        out[(size_t)(lane & 7) * N_DIM + r] = total * scales[r];
    }
}

extern "C" void kernel_launch(void* const* d_in, const int* in_sizes, int n_in,
                              void* d_out, int out_size, void* d_ws, size_t ws_size,
                              hipStream_t stream) {
    const float* x      = (const float*)d_in[0];
    const int*   w      = (const int*)d_in[1];
    const float* scales = (const float*)d_in[2];
    float*       out    = (float*)d_out;

    dim3 grid(N_DIM / ROWS_PER_BLOCK);   // 512
    dim3 block(BLOCK);                   // 512
    hipLaunchKernelGGL(w4a16_gemv, grid, block, 0, stream, x, w, scales, out);
}

// Round 3
// 197.488 us; speedup vs baseline: 1.4952x; 1.4952x over previous
//
#include <hip/hip_runtime.h>
#include <hip/hip_bf16.h>
#include <stdint.h>

#define BATCH 8
#define K_DIM 4096
#define N_DIM 16384
#define KH (K_DIM / 2)          // 2048 packed ints per output row
#define BLOCK 512               // 8 waves
#define ROWS_PER_WAVE 4
#define ROWS_PER_BLOCK 32       // 8 waves * 4 rows
#define ITERS (KH / 4 / 64)     // 8 iterations of int4 per lane

__device__ __forceinline__ float bf16lo(uint32_t u) { return __uint_as_float(u << 16); }
__device__ __forceinline__ float bf16hi(uint32_t u) { return __uint_as_float(u & 0xFFFF0000u); }

// RNE f32 -> bf16 (returns the 16-bit pattern in the low half)
__device__ __forceinline__ uint32_t f32_to_bf16_bits(float f) {
    uint32_t u = __float_as_uint(f);
    return (u + 0x7FFFu + ((u >> 16) & 1u)) >> 16;
}

// LDS: xchunks[phys] (uint4) = column c's 8 batches as bf16,
// phys = c ^ ((c>>3)&7). Within any 8 consecutive logical columns the
// physical chunks hit all 8 quad-bank groups -> b128 reads/writes are
// conflict-free in 8-lane groups.
__global__ __launch_bounds__(BLOCK, 2)
void w4a16_gemv(const float* __restrict__ x,       // [8][4096] f32 (fp16 upcast)
                const int*   __restrict__ w,       // [16384][2048] int32 (byte each)
                const float* __restrict__ scales,  // [16384] f32
                float*       __restrict__ out)     // [8][16384] f32
{
    __shared__ uint4 xchunks[K_DIM];   // 64 KiB
    const int tid = threadIdx.x;

    // ---- stage x -> LDS: one thread per column, ds_write_b128 ----
    #pragma unroll
    for (int t = 0; t < K_DIM / BLOCK; ++t) {      // 8 iterations
        const int c = t * BLOCK + tid;
        float v[BATCH];
        #pragma unroll
        for (int b = 0; b < BATCH; ++b) v[b] = x[b * K_DIM + c];
        uint4 pk;
        pk.x = f32_to_bf16_bits(v[0]) | (f32_to_bf16_bits(v[1]) << 16);
        pk.y = f32_to_bf16_bits(v[2]) | (f32_to_bf16_bits(v[3]) << 16);
        pk.z = f32_to_bf16_bits(v[4]) | (f32_to_bf16_bits(v[5]) << 16);
        pk.w = f32_to_bf16_bits(v[6]) | (f32_to_bf16_bits(v[7]) << 16);
        xchunks[c ^ ((c >> 3) & 7)] = pk;
    }
    __syncthreads();

    const int wave = tid >> 6;
    const int lane = tid & 63;
    const int row0 = blockIdx.x * ROWS_PER_BLOCK + wave * ROWS_PER_WAVE;

    const int4* __restrict__ wv0 = (const int4*)(w + (size_t)(row0 + 0) * KH);
    const int4* __restrict__ wv1 = (const int4*)(w + (size_t)(row0 + 1) * KH);
    const int4* __restrict__ wv2 = (const int4*)(w + (size_t)(row0 + 2) * KH);
    const int4* __restrict__ wv3 = (const int4*)(w + (size_t)(row0 + 3) * KH);

    float acc[ROWS_PER_WAVE][BATCH];
    #pragma unroll
    for (int j = 0; j < ROWS_PER_WAVE; ++j)
        #pragma unroll
        for (int b = 0; b < BATCH; ++b) acc[j][b] = 0.0f;

    #pragma unroll 1
    for (int t = 0; t < ITERS; ++t) {
        const int u = (t << 6) + lane;       // int4 index within row
        int4 q0 = wv0[u];
        int4 q1 = wv1[u];
        int4 q2 = wv2[u];
        int4 q3 = wv3[u];
        const int xork  = u & 7;
        const int cbase = u << 3;            // chunk base (column 8u)

        int qw[ROWS_PER_WAVE][4];
        qw[0][0] = q0.x; qw[0][1] = q0.y; qw[0][2] = q0.z; qw[0][3] = q0.w;
        qw[1][0] = q1.x; qw[1][1] = q1.y; qw[1][2] = q1.z; qw[1][3] = q1.w;
        qw[2][0] = q2.x; qw[2][1] = q2.y; qw[2][2] = q2.z; qw[2][3] = q2.w;
        qw[3][0] = q3.x; qw[3][1] = q3.y; qw[3][2] = q3.z; qw[3][3] = q3.w;

        #pragma unroll
        for (int m = 0; m < 4; ++m) {
            // packed int p = 4u+m covers columns 8u+2m (low nibble), 8u+2m+1 (high)
            const uint4 xa = xchunks[cbase + ((2 * m)     ^ xork)];
            const uint4 xb = xchunks[cbase + ((2 * m + 1) ^ xork)];

            float xlo[BATCH], xhi[BATCH];
            xlo[0] = bf16lo(xa.x); xlo[1] = bf16hi(xa.x);
            xlo[2] = bf16lo(xa.y); xlo[3] = bf16hi(xa.y);
            xlo[4] = bf16lo(xa.z); xlo[5] = bf16hi(xa.z);
            xlo[6] = bf16lo(xa.w); xlo[7] = bf16hi(xa.w);
            xhi[0] = bf16lo(xb.x); xhi[1] = bf16hi(xb.x);
            xhi[2] = bf16lo(xb.y); xhi[3] = bf16hi(xb.y);
            xhi[4] = bf16lo(xb.z); xhi[5] = bf16hi(xb.z);
            xhi[6] = bf16lo(xb.w); xhi[7] = bf16hi(xb.w);

            #pragma unroll
            for (int j = 0; j < ROWS_PER_WAVE; ++j) {
                const unsigned bv = ((unsigned)qw[j][m]) & 0xFFu;
                const float flo = (float)((int)((bv & 0xFu) ^ 8u) - 8);
                const float fhi = (float)((int)(((bv >> 4) & 0xFu) ^ 8u) - 8);
                #pragma unroll
                for (int b = 0; b < BATCH; ++b) {
                    acc[j][b] = fmaf(flo, xlo[b], acc[j][b]);
                    acc[j][b] = fmaf(fhi, xhi[b], acc[j][b]);
                }
            }
        }
    }

    // ---- 32-value tree reduction; value j*8+b lands on lane j*8+b ----
    float vals[32];
    #pragma unroll
    for (int j = 0; j < ROWS_PER_WAVE; ++j)
        #pragma unroll
        for (int b = 0; b < BATCH; ++b) vals[j * 8 + b] = acc[j][b];

    #pragma unroll
    for (int k = 0; k < 5; ++k) {
        const int sel = (lane >> k) & 1;
        const int n = 32 >> k;
        #pragma unroll
        for (int i = 0; i < n / 2; ++i) {
            const float a = vals[2 * i];
            const float c = vals[2 * i + 1];
            const float mine  = sel ? c : a;
            const float other = sel ? a : c;
            vals[i] = mine + __shfl_xor(other, 1 << k, 64);
        }
    }
    const float total = vals[0] + __shfl_xor(vals[0], 32, 64);

    if (lane < 32) {
        const int r = row0 + (lane >> 3);      // j = lane>>3, b = lane&7
        out[(size_t)(lane & 7) * N_DIM + r] = total * scales[r];
    }
}

extern "C" void kernel_launch(void* const* d_in, const int* in_sizes, int n_in,
                              void* d_out, int out_size, void* d_ws, size_t ws_size,
                              hipStream_t stream) {
    const float* x      = (const float*)d_in[0];
    const int*   w      = (const int*)d_in[1];
    const float* scales = (const float*)d_in[2];
    float*       out    = (float*)d_out;

    dim3 grid(N_DIM / ROWS_PER_BLOCK);   // 512
    dim3 block(BLOCK);                   // 512
    hipLaunchKernelGGL(w4a16_gemv, grid, block, 0, stream, x, w, scales, out);
}